// Round 1
// baseline (139.401 us; speedup 1.0000x reference)
//
#include <hip/hip_runtime.h>
#include <math.h>

#define BATCH 64
#define DIM 1024
#define NROW (BATCH * DIM)        // 65536 rows of C
// d_out layout (floats): h[65536] | C_new[67108864] | n_new[65536] | m_new[65536]
#define OFF_H 0
#define OFF_C 65536
#define OFF_N (65536 + 67108864)
#define OFF_M (OFF_N + 65536)

// ws layout (floats): pre[6][NROW], gate order 0:q 1:k 2:v 3:i 4:f 5:o
// after `derive`: slot0=q, slot1=k/32, slot2=i*v, slot4=f, slot5=sigmoid(o)

// ---------------------------------------------------------------------------
// Kernel 1: six GEMMs  pre[g][b][j] = sum_d x[b,d]*W_g[j,d] + bias_g[j]
// grid = 6 gates * 64 col-tiles = 384 blocks, 256 threads.
// BM=64 (all b), BN=16, BK=64. LDS tiles stored K-major so the inner loop
// reads xs as float4 (ds_read_b128) and W as broadcast scalar.
// ---------------------------------------------------------------------------
__global__ __launch_bounds__(256) void gemm6(
    const float* __restrict__ x,
    const float* __restrict__ Wq, const float* __restrict__ bq,
    const float* __restrict__ Wk, const float* __restrict__ bk,
    const float* __restrict__ Wv, const float* __restrict__ bv,
    const float* __restrict__ Wi, const float* __restrict__ bi,
    const float* __restrict__ Wf, const float* __restrict__ bf,
    const float* __restrict__ Wo, const float* __restrict__ bo,
    float* __restrict__ pre)
{
    __shared__ float xs[64][64];   // [kk][b]   (reads: 4 addrs/wave, conflict-free)
    __shared__ float wl[64][17];   // [kk][jj]  (+1 pad keeps staging writes 2-way)

    const int bx = blockIdx.x;
    const int g = bx >> 6;             // gate
    const int j0 = (bx & 63) * 16;     // column tile
    const float* W; const float* bias;
    switch (g) {
        case 0: W = Wq; bias = bq; break;
        case 1: W = Wk; bias = bk; break;
        case 2: W = Wv; bias = bv; break;
        case 3: W = Wi; bias = bi; break;
        case 4: W = Wf; bias = bf; break;
        default: W = Wo; bias = bo; break;
    }

    const int tid = threadIdx.x;
    const int tj = tid & 15;           // output column within tile
    const int tb = tid >> 4;           // 0..15, each covers 4 batch rows

    const int xb = tid & 63;           // x staging: batch row
    const int xc = tid >> 6;           // x staging: float4 group 0..3
    const int wj = tid >> 4;           // W staging: row within tile 0..15
    const int wk = tid & 15;           // W staging: float4 index 0..15

    float acc[4] = {0.f, 0.f, 0.f, 0.f};

    for (int k0 = 0; k0 < DIM; k0 += 64) {
        // stage x[0..63][k0..k0+63] -> xs[kk][b]
        #pragma unroll
        for (int it = 0; it < 4; ++it) {
            const int cq = xc * 4 + it;   // float4 index along K, 0..15
            float4 v = *reinterpret_cast<const float4*>(&x[xb * DIM + k0 + cq * 4]);
            xs[cq * 4 + 0][xb] = v.x;
            xs[cq * 4 + 1][xb] = v.y;
            xs[cq * 4 + 2][xb] = v.z;
            xs[cq * 4 + 3][xb] = v.w;
        }
        // stage W[j0..j0+15][k0..k0+63] -> wl[kk][jj]
        {
            float4 v = *reinterpret_cast<const float4*>(&W[(j0 + wj) * DIM + k0 + wk * 4]);
            wl[wk * 4 + 0][wj] = v.x;
            wl[wk * 4 + 1][wj] = v.y;
            wl[wk * 4 + 2][wj] = v.z;
            wl[wk * 4 + 3][wj] = v.w;
        }
        __syncthreads();
        #pragma unroll
        for (int kk = 0; kk < 64; ++kk) {
            float4 xv = *reinterpret_cast<const float4*>(&xs[kk][tb * 4]);
            float wv = wl[kk][tj];
            acc[0] += xv.x * wv;
            acc[1] += xv.y * wv;
            acc[2] += xv.z * wv;
            acc[3] += xv.w * wv;
        }
        __syncthreads();
    }

    const float bv_ = bias[j0 + tj];
    const int jcol = j0 + tj;
    #pragma unroll
    for (int e = 0; e < 4; ++e) {
        const int b = tb * 4 + e;
        pre[g * NROW + b * DIM + jcol] = acc[e] + bv_;
    }
}

// ---------------------------------------------------------------------------
// Kernel 2: element-wise gate derivation. 65536 threads.
// ---------------------------------------------------------------------------
__global__ __launch_bounds__(256) void derive(
    const float* __restrict__ n_in, const float* __restrict__ m_in,
    float* __restrict__ ws, float* __restrict__ out)
{
    const int idx = blockIdx.x * 256 + threadIdx.x;   // 0..65535
    const float kp  = ws[1 * NROW + idx];
    const float vp  = ws[2 * NROW + idx];
    const float ip  = ws[3 * NROW + idx];
    const float fp_ = ws[4 * NROW + idx];
    const float op  = ws[5 * NROW + idx];
    const float mo = m_in[idx];
    const float no = n_in[idx];

    const float ks  = kp * 0.03125f;                  // /sqrt(1024)
    const float mn  = fmaxf(fp_ + mo, ip);
    const float iex = expf(ip - mn);
    const float fex = expf(fp_ + mo - mn);
    const float so  = 1.f / (1.f + expf(-op));

    ws[1 * NROW + idx] = ks;
    ws[2 * NROW + idx] = iex * vp;
    ws[4 * NROW + idx] = fex;
    ws[5 * NROW + idx] = so;
    out[OFF_N + idx] = fex * no + iex * ks;
    out[OFF_M + idx] = mn;
}

// ---------------------------------------------------------------------------
// Kernel 3: the streaming pass. One wave per (b,r) row of C.
//   C_new[b,r,c] = f[b,r]*C[b,r,c] + (i*v)[b,r]*k[b,c]
//   h[b,r] = sigmoid(o)[b,r] * sum_c C_new[b,r,c]*q[b,c]
// 536 MB HBM traffic -> memory-bound, float4 fully-coalesced.
// ---------------------------------------------------------------------------
__global__ __launch_bounds__(256) void cupdate(
    const float* __restrict__ C,
    const float* __restrict__ ws,
    float* __restrict__ out)
{
    const int row  = blockIdx.x * 4 + (threadIdx.x >> 6);   // 0..65535
    const int lane = threadIdx.x & 63;
    const int b    = row >> 10;

    const float f_r = ws[4 * NROW + row];
    const float iv  = ws[2 * NROW + row];
    const float so  = ws[5 * NROW + row];

    const float4* k4 = reinterpret_cast<const float4*>(ws + 1 * NROW + b * DIM);
    const float4* q4 = reinterpret_cast<const float4*>(ws + 0 * NROW + b * DIM);
    const float4* C4 = reinterpret_cast<const float4*>(C) + (size_t)row * 256;
    float4*       O4 = reinterpret_cast<float4*>(out + OFF_C) + (size_t)row * 256;

    float dot = 0.f;
    #pragma unroll
    for (int i = 0; i < 4; ++i) {
        const int c4 = lane + 64 * i;          // float4 column index, coalesced
        float4 cv = C4[c4];
        float4 kv = k4[c4];
        float4 qv = q4[c4];
        float4 cn;
        cn.x = f_r * cv.x + iv * kv.x;
        cn.y = f_r * cv.y + iv * kv.y;
        cn.z = f_r * cv.z + iv * kv.z;
        cn.w = f_r * cv.w + iv * kv.w;
        O4[c4] = cn;
        dot += cn.x * qv.x + cn.y * qv.y + cn.z * qv.z + cn.w * qv.w;
    }
    // wave-wide sum (64 lanes)
    #pragma unroll
    for (int off = 32; off > 0; off >>= 1)
        dot += __shfl_xor(dot, off, 64);
    if (lane == 0)
        out[OFF_H + row] = so * dot;
}

extern "C" void kernel_launch(void* const* d_in, const int* in_sizes, int n_in,
                              void* d_out, int out_size, void* d_ws, size_t ws_size,
                              hipStream_t stream) {
    const float* x = (const float*)d_in[0];
    const float* C = (const float*)d_in[1];
    const float* n = (const float*)d_in[2];
    const float* m = (const float*)d_in[3];
    float* ws  = (float*)d_ws;    // needs 6*65536*4 = 1.5 MB
    float* out = (float*)d_out;

    gemm6<<<384, 256, 0, stream>>>(
        x,
        (const float*)d_in[4],  (const float*)d_in[5],
        (const float*)d_in[6],  (const float*)d_in[7],
        (const float*)d_in[8],  (const float*)d_in[9],
        (const float*)d_in[10], (const float*)d_in[11],
        (const float*)d_in[12], (const float*)d_in[13],
        (const float*)d_in[14], (const float*)d_in[15],
        ws);
    derive<<<NROW / 256, 256, 0, stream>>>(n, m, ws, out);
    cupdate<<<NROW / 4, 256, 0, stream>>>(C, ws, out);
}

// Round 3
// 135.623 us; speedup vs baseline: 1.0279x; 1.0279x over previous
//
#include <hip/hip_runtime.h>
#include <math.h>

#define BATCH 64
#define DIM 1024
#define NROW (BATCH * DIM)        // 65536 rows of C
// d_out layout (floats): h[65536] | C_new[67108864] | n_new[65536] | m_new[65536]
#define OFF_H 0
#define OFF_C 65536
#define OFF_N (65536 + 67108864)
#define OFF_M (OFF_N + 65536)

typedef float f4 __attribute__((ext_vector_type(4)));   // native vector: OK for nontemporal builtins

// ws layout (floats): pre[6][NROW], gate order 0:q 1:k 2:v 3:i 4:f 5:o
// (raw pre-activations incl. bias; all gate nonlinearity fused into cupdate)

// ---------------------------------------------------------------------------
// Kernel 1: six GEMMs  pre[g][b][j] = sum_d x[b,d]*W_g[j,d] + bias_g[j]
// grid = 6 gates * 64 col-tiles = 384 blocks, 256 threads.
// ---------------------------------------------------------------------------
__global__ __launch_bounds__(256) void gemm6(
    const float* __restrict__ x,
    const float* __restrict__ Wq, const float* __restrict__ bq,
    const float* __restrict__ Wk, const float* __restrict__ bk,
    const float* __restrict__ Wv, const float* __restrict__ bv,
    const float* __restrict__ Wi, const float* __restrict__ bi,
    const float* __restrict__ Wf, const float* __restrict__ bf,
    const float* __restrict__ Wo, const float* __restrict__ bo,
    float* __restrict__ pre)
{
    __shared__ float xs[64][64];   // [kk][b]
    __shared__ float wl[64][17];   // [kk][jj]  (+1 pad)

    const int bx = blockIdx.x;
    const int g = bx >> 6;             // gate
    const int j0 = (bx & 63) * 16;     // column tile
    const float* W; const float* bias;
    switch (g) {
        case 0: W = Wq; bias = bq; break;
        case 1: W = Wk; bias = bk; break;
        case 2: W = Wv; bias = bv; break;
        case 3: W = Wi; bias = bi; break;
        case 4: W = Wf; bias = bf; break;
        default: W = Wo; bias = bo; break;
    }

    const int tid = threadIdx.x;
    const int tj = tid & 15;           // output column within tile
    const int tb = tid >> 4;           // 0..15, each covers 4 batch rows

    const int xb = tid & 63;           // x staging: batch row
    const int xc = tid >> 6;           // x staging: float4 group 0..3
    const int wj = tid >> 4;           // W staging: row within tile 0..15
    const int wk = tid & 15;           // W staging: float4 index 0..15

    float acc[4] = {0.f, 0.f, 0.f, 0.f};

    for (int k0 = 0; k0 < DIM; k0 += 64) {
        #pragma unroll
        for (int it = 0; it < 4; ++it) {
            const int cq = xc * 4 + it;   // float4 index along K, 0..15
            float4 v = *reinterpret_cast<const float4*>(&x[xb * DIM + k0 + cq * 4]);
            xs[cq * 4 + 0][xb] = v.x;
            xs[cq * 4 + 1][xb] = v.y;
            xs[cq * 4 + 2][xb] = v.z;
            xs[cq * 4 + 3][xb] = v.w;
        }
        {
            float4 v = *reinterpret_cast<const float4*>(&W[(j0 + wj) * DIM + k0 + wk * 4]);
            wl[wk * 4 + 0][wj] = v.x;
            wl[wk * 4 + 1][wj] = v.y;
            wl[wk * 4 + 2][wj] = v.z;
            wl[wk * 4 + 3][wj] = v.w;
        }
        __syncthreads();
        #pragma unroll
        for (int kk = 0; kk < 64; ++kk) {
            float4 xv = *reinterpret_cast<const float4*>(&xs[kk][tb * 4]);
            float wv = wl[kk][tj];
            acc[0] += xv.x * wv;
            acc[1] += xv.y * wv;
            acc[2] += xv.z * wv;
            acc[3] += xv.w * wv;
        }
        __syncthreads();
    }

    const float bv_ = bias[j0 + tj];
    const int jcol = j0 + tj;
    #pragma unroll
    for (int e = 0; e < 4; ++e) {
        const int b = tb * 4 + e;
        pre[g * NROW + b * DIM + jcol] = acc[e] + bv_;
    }
}

// ---------------------------------------------------------------------------
// Kernel 2 (fused): gate math + rank-1 C update + h dot + n_new/m_new.
// One wave per (b,r) row of C. Non-temporal on the 536 MB C stream;
// q/k rows (8 KB per batch) stay cached (reused by 1024 rows).
// ---------------------------------------------------------------------------
__global__ __launch_bounds__(256) void cupdate(
    const float* __restrict__ C,
    const float* __restrict__ n_in, const float* __restrict__ m_in,
    const float* __restrict__ ws,
    float* __restrict__ out)
{
    const int row  = blockIdx.x * 4 + (threadIdx.x >> 6);   // 0..65535
    const int lane = threadIdx.x & 63;
    const int b    = row >> 10;

    // per-row gate scalars (wave-uniform broadcast loads)
    const float ip  = ws[3 * NROW + row];
    const float fp_ = ws[4 * NROW + row];
    const float op  = ws[5 * NROW + row];
    const float vp  = ws[2 * NROW + row];
    const float mo  = m_in[row];

    const float mn  = fmaxf(fp_ + mo, ip);
    const float iex = expf(ip - mn);
    const float fex = expf(fp_ + mo - mn);
    const float so  = 1.f / (1.f + expf(-op));
    const float iv  = iex * vp;

    const f4* k4 = reinterpret_cast<const f4*>(ws + 1 * NROW + b * DIM); // pre_k
    const f4* q4 = reinterpret_cast<const f4*>(ws + 0 * NROW + b * DIM); // q
    const f4* C4 = reinterpret_cast<const f4*>(C) + (size_t)row * 256;
    f4*       O4 = reinterpret_cast<f4*>(out + OFF_C) + (size_t)row * 256;

    const float ksc = iv * 0.03125f;   // fold the 1/sqrt(DIM) k-scale into iv

    float dot = 0.f;
    #pragma unroll
    for (int i = 0; i < 4; ++i) {
        const int c4 = lane + 64 * i;          // float4 column index, coalesced
        f4 cv = __builtin_nontemporal_load(&C4[c4]);
        f4 kv = k4[c4];
        f4 qv = q4[c4];
        f4 cn = fex * cv + ksc * kv;
        __builtin_nontemporal_store(cn, &O4[c4]);
        f4 pr = cn * qv;
        dot += pr.x + pr.y + pr.z + pr.w;
    }
    // wave-wide sum (64 lanes)
    #pragma unroll
    for (int off = 32; off > 0; off >>= 1)
        dot += __shfl_xor(dot, off, 64);

    if (lane == 0) {
        out[OFF_H + row] = so * dot;
        const float no   = n_in[row];
        const float kp_r = ws[1 * NROW + row] * 0.03125f;
        out[OFF_N + row] = fex * no + iex * kp_r;
        out[OFF_M + row] = mn;
    }
}

extern "C" void kernel_launch(void* const* d_in, const int* in_sizes, int n_in,
                              void* d_out, int out_size, void* d_ws, size_t ws_size,
                              hipStream_t stream) {
    const float* x = (const float*)d_in[0];
    const float* C = (const float*)d_in[1];
    const float* n = (const float*)d_in[2];
    const float* m = (const float*)d_in[3];
    float* ws  = (float*)d_ws;    // needs 6*65536*4 = 1.5 MB
    float* out = (float*)d_out;

    gemm6<<<384, 256, 0, stream>>>(
        x,
        (const float*)d_in[4],  (const float*)d_in[5],
        (const float*)d_in[6],  (const float*)d_in[7],
        (const float*)d_in[8],  (const float*)d_in[9],
        (const float*)d_in[10], (const float*)d_in[11],
        (const float*)d_in[12], (const float*)d_in[13],
        (const float*)d_in[14], (const float*)d_in[15],
        ws);
    cupdate<<<NROW / 4, 256, 0, stream>>>(C, n, m, ws, out);
}

// Round 4
// 129.645 us; speedup vs baseline: 1.0752x; 1.0461x over previous
//
#include <hip/hip_runtime.h>
#include <hip/hip_bf16.h>
#include <math.h>

#define BATCH 64
#define DIM 1024
#define NROW (BATCH * DIM)        // 65536 rows of C
// d_out layout (floats): h[65536] | C_new[67108864] | n_new[65536] | m_new[65536]
#define OFF_H 0
#define OFF_C 65536
#define OFF_N (65536 + 67108864)
#define OFF_M (OFF_N + 65536)

typedef float f4     __attribute__((ext_vector_type(4)));   // native vec (nontemporal-ok)
typedef float f32x4  __attribute__((ext_vector_type(4)));   // MFMA C/D frag
typedef short bf16x8 __attribute__((ext_vector_type(8)));   // MFMA A/B frag (8 bf16)

// ws layout (floats): pre[6][NROW], gate order 0:q 1:k 2:v 3:i 4:f 5:o
// (raw pre-activations incl. bias; gate nonlinearity fused into cupdate)

__device__ inline short f2bf(float v) {
    __hip_bfloat16 h = __float2bfloat16(v);   // RNE convert
    short s;
    __builtin_memcpy(&s, &h, 2);
    return s;
}

__device__ inline bf16x8 load_bf8(const float* __restrict__ p) {
    f4 a = *reinterpret_cast<const f4*>(p);
    f4 b = *reinterpret_cast<const f4*>(p + 4);
    bf16x8 r;
    r[0] = f2bf(a.x); r[1] = f2bf(a.y); r[2] = f2bf(a.z); r[3] = f2bf(a.w);
    r[4] = f2bf(b.x); r[5] = f2bf(b.y); r[6] = f2bf(b.z); r[7] = f2bf(b.w);
    return r;
}

// ---------------------------------------------------------------------------
// Kernel 1: six GEMMs via bf16 MFMA.  pre[g][b][j] = sum_d x[b,d]*W_g[j,d] + b_g[j]
// grid = 6 gates * 64 col-tiles = 384 blocks, 256 threads (4 waves).
// Wave w computes batch rows [16w,16w+16) x cols [j0,j0+16), K=1024 in 32 steps.
// No LDS: per lane both operand frags are 32B contiguous global loads
// (x L2-resident; W streamed once). A-frag row=lane&15, k=8*(lane>>4)+j;
// B-frag col=lane&15 (same k-map). D: col=lane&15, row=(lane>>4)*4+reg [m89].
// ---------------------------------------------------------------------------
__global__ __launch_bounds__(256) void gemm6_mfma(
    const float* __restrict__ x,
    const float* __restrict__ Wq, const float* __restrict__ bq,
    const float* __restrict__ Wk, const float* __restrict__ bk,
    const float* __restrict__ Wv, const float* __restrict__ bv,
    const float* __restrict__ Wi, const float* __restrict__ bi,
    const float* __restrict__ Wf, const float* __restrict__ bf_,
    const float* __restrict__ Wo, const float* __restrict__ bo,
    float* __restrict__ pre)
{
    const int bx = blockIdx.x;
    const int g  = bx >> 6;             // gate
    const int j0 = (bx & 63) << 4;      // 16-col tile
    const float* W; const float* bias;
    switch (g) {
        case 0: W = Wq; bias = bq; break;
        case 1: W = Wk; bias = bk; break;
        case 2: W = Wv; bias = bv; break;
        case 3: W = Wi; bias = bi; break;
        case 4: W = Wf; bias = bf_; break;
        default: W = Wo; bias = bo; break;
    }

    const int wave = threadIdx.x >> 6;
    const int lane = threadIdx.x & 63;
    const int l15  = lane & 15;
    const int kq   = lane >> 4;         // 0..3

    const float* xrow = x + (size_t)(wave * 16 + l15) * DIM + kq * 8;
    const float* wrow = W + (size_t)(j0 + l15) * DIM + kq * 8;

    f32x4 acc0 = {0.f, 0.f, 0.f, 0.f};
    f32x4 acc1 = {0.f, 0.f, 0.f, 0.f};
    #pragma unroll 4
    for (int kt = 0; kt < 32; kt += 2) {
        bf16x8 a0 = load_bf8(xrow + kt * 32);
        bf16x8 b0 = load_bf8(wrow + kt * 32);
        bf16x8 a1 = load_bf8(xrow + kt * 32 + 32);
        bf16x8 b1 = load_bf8(wrow + kt * 32 + 32);
        acc0 = __builtin_amdgcn_mfma_f32_16x16x32_bf16(a0, b0, acc0, 0, 0, 0);
        acc1 = __builtin_amdgcn_mfma_f32_16x16x32_bf16(a1, b1, acc1, 0, 0, 0);
    }
    acc0 += acc1;

    const float bv_ = bias[j0 + l15];           // D col = lane&15
    float* dst = pre + (size_t)g * NROW + (size_t)(wave * 16 + kq * 4) * DIM + j0 + l15;
    #pragma unroll
    for (int r = 0; r < 4; ++r)
        dst[(size_t)r * DIM] = acc0[r] + bv_;   // D row = kq*4 + r
}

// ---------------------------------------------------------------------------
// Kernel 2 (fused): gate math + rank-1 C update + h dot + n_new/m_new.
// One wave per (b,r) row of C. Non-temporal on the 536 MB C stream;
// q/k rows (8 KB per batch) stay cached (reused by 1024 rows).
// ---------------------------------------------------------------------------
__global__ __launch_bounds__(256) void cupdate(
    const float* __restrict__ C,
    const float* __restrict__ n_in, const float* __restrict__ m_in,
    const float* __restrict__ ws,
    float* __restrict__ out)
{
    const int row  = blockIdx.x * 4 + (threadIdx.x >> 6);   // 0..65535
    const int lane = threadIdx.x & 63;
    const int b    = row >> 10;

    // per-row gate scalars (wave-uniform broadcast loads)
    const float ip  = ws[3 * NROW + row];
    const float fp_ = ws[4 * NROW + row];
    const float op  = ws[5 * NROW + row];
    const float vp  = ws[2 * NROW + row];
    const float mo  = m_in[row];

    const float mn  = fmaxf(fp_ + mo, ip);
    const float iex = expf(ip - mn);
    const float fex = expf(fp_ + mo - mn);
    const float so  = 1.f / (1.f + expf(-op));
    const float iv  = iex * vp;

    const f4* k4 = reinterpret_cast<const f4*>(ws + 1 * NROW + b * DIM); // pre_k
    const f4* q4 = reinterpret_cast<const f4*>(ws + 0 * NROW + b * DIM); // q
    const f4* C4 = reinterpret_cast<const f4*>(C) + (size_t)row * 256;
    f4*       O4 = reinterpret_cast<f4*>(out + OFF_C) + (size_t)row * 256;

    const float ksc = iv * 0.03125f;   // fold 1/sqrt(DIM) into i*v

    float dot = 0.f;
    #pragma unroll
    for (int i = 0; i < 4; ++i) {
        const int c4 = lane + 64 * i;          // float4 column index, coalesced
        f4 cv = __builtin_nontemporal_load(&C4[c4]);
        f4 kv = k4[c4];
        f4 qv = q4[c4];
        f4 cn = fex * cv + ksc * kv;
        __builtin_nontemporal_store(cn, &O4[c4]);
        f4 pr = cn * qv;
        dot += pr.x + pr.y + pr.z + pr.w;
    }
    // wave-wide sum (64 lanes)
    #pragma unroll
    for (int off = 32; off > 0; off >>= 1)
        dot += __shfl_xor(dot, off, 64);

    if (lane == 0) {
        out[OFF_H + row] = so * dot;
        const float no   = n_in[row];
        const float kp_r = ws[1 * NROW + row] * 0.03125f;
        out[OFF_N + row] = fex * no + iex * kp_r;
        out[OFF_M + row] = mn;
    }
}

extern "C" void kernel_launch(void* const* d_in, const int* in_sizes, int n_in,
                              void* d_out, int out_size, void* d_ws, size_t ws_size,
                              hipStream_t stream) {
    const float* x = (const float*)d_in[0];
    const float* C = (const float*)d_in[1];
    const float* n = (const float*)d_in[2];
    const float* m = (const float*)d_in[3];
    float* ws  = (float*)d_ws;    // needs 6*65536*4 = 1.5 MB
    float* out = (float*)d_out;

    gemm6_mfma<<<384, 256, 0, stream>>>(
        x,
        (const float*)d_in[4],  (const float*)d_in[5],
        (const float*)d_in[6],  (const float*)d_in[7],
        (const float*)d_in[8],  (const float*)d_in[9],
        (const float*)d_in[10], (const float*)d_in[11],
        (const float*)d_in[12], (const float*)d_in[13],
        (const float*)d_in[14], (const float*)d_in[15],
        ws);
    cupdate<<<NROW / 4, 256, 0, stream>>>(C, n, m, ws, out);
}